// Round 2
// baseline (78.979 us; speedup 1.0000x reference)
//
#include <hip/hip_runtime.h>

#define IMG 100
#define OUTD 50
#define NPATCH 2500
#define NB 5
#define NGATE (NB * 8)  // per block: 4 u3 + 4 cu3
#define NBLK ((NPATCH + 63) / 64)  // 40 blocks of one wave each

__device__ __forceinline__ float2 cmul(float2 a, float2 b) {
    return make_float2(a.x * b.x - a.y * b.y, a.x * b.y + a.y * b.x);
}
__device__ __forceinline__ float2 cadd(float2 a, float2 b) {
    return make_float2(a.x + b.x, a.y + b.y);
}

// Fully fused: patch sim + feature@W + log_softmax.
// One thread per patch (16 complex amps in registers), one wave per block.
// Per-block partial logits -> wave shuffle reduce -> atomicAdd into ws.
// Last-arriving block (atomic ticket) applies bias + log_softmax, writes out.
__global__ __launch_bounds__(64) void qconv_fused(
    const float* __restrict__ img,
    const float* __restrict__ u3p,
    const float* __restrict__ cu3p,
    const float* __restrict__ W,
    const float* __restrict__ bias,
    float* __restrict__ ws_logits,   // 8 floats, zeroed by memsetAsync
    unsigned* __restrict__ ws_count, // 1 uint, zeroed
    float* __restrict__ out)
{
    __shared__ float2 gm[NGATE][4];  // [gate][m00,m01,m10,m11]
    const int tid = threadIdx.x;

    if (tid < NGATE) {
        const int blk = tid >> 3;
        const int idx = tid & 7;
        const float* pp = (idx < 4) ? &u3p[(blk * 4 + idx) * 3]
                                    : &cu3p[(blk * 4 + (idx - 4)) * 3];
        const float th = pp[0], ph = pp[1], la = pp[2];
        float s, c, sl, cl, sp, cp, spl, cpl;
        __sincosf(th * 0.5f, &s, &c);
        __sincosf(la, &sl, &cl);
        __sincosf(ph, &sp, &cp);
        __sincosf(ph + la, &spl, &cpl);
        gm[tid][0] = make_float2(c, 0.0f);           // m00 = cos(th/2)
        gm[tid][1] = make_float2(-cl * s, -sl * s);  // m01 = -e^{i la} sin
        gm[tid][2] = make_float2(cp * s, sp * s);    // m10 =  e^{i ph} sin
        gm[tid][3] = make_float2(cpl * c, spl * c);  // m11 =  e^{i(ph+la)} cos
    }
    __syncthreads();

    const int p = blockIdx.x * 64 + tid;
    const bool active = (p < NPATCH);
    const int pcl = active ? p : (NPATCH - 1);  // clamp for safe loads

    const int rb = pcl / OUTD;
    const int cb = pcl - rb * OUTD;
    const int i0 = 2 * rb, j0 = 2 * cb;

    // patch pixels, row-major within patch; wire w uses pixel w
    float x0 = img[i0 * IMG + j0];
    float x1 = img[i0 * IMG + j0 + 1];
    float x2 = img[(i0 + 1) * IMG + j0];
    float x3 = img[(i0 + 1) * IMG + j0 + 1];

    float v[4][2];
    __sincosf(x0 * 0.5f, &v[0][1], &v[0][0]);  // RY(x)|0> = [cos, sin]
    __sincosf(x1 * 0.5f, &v[1][1], &v[1][0]);
    __sincosf(x2 * 0.5f, &v[2][1], &v[2][0]);
    __sincosf(x3 * 0.5f, &v[3][1], &v[3][0]);

    // amp index: bit (3-w) is wire w's basis bit (wire 0 = MSB)
    float2 amp[16];
#pragma unroll
    for (int i = 0; i < 16; ++i) {
        const int b0 = (i >> 3) & 1, b1 = (i >> 2) & 1, b2 = (i >> 1) & 1, b3 = i & 1;
        amp[i] = make_float2(v[0][b0] * v[1][b1] * v[2][b2] * v[3][b3], 0.0f);
    }

    const int pt[4] = {1, 2, 3, 0};  // ctrl k -> tgt pt[k]

#pragma unroll
    for (int blk = 0; blk < NB; ++blk) {
#pragma unroll
        for (int w = 0; w < 4; ++w) {
            const float2 m0 = gm[blk * 8 + w][0];
            const float2 m1 = gm[blk * 8 + w][1];
            const float2 m2 = gm[blk * 8 + w][2];
            const float2 m3 = gm[blk * 8 + w][3];
            const int sw = 1 << (3 - w);
#pragma unroll
            for (int i = 0; i < 16; ++i) {
                if ((i & sw) == 0) {
                    const float2 a0 = amp[i], a1 = amp[i + sw];
                    amp[i]      = cadd(cmul(m0, a0), cmul(m1, a1));
                    amp[i + sw] = cadd(cmul(m2, a0), cmul(m3, a1));
                }
            }
        }
#pragma unroll
        for (int k = 0; k < 4; ++k) {
            const float2 m0 = gm[blk * 8 + 4 + k][0];
            const float2 m1 = gm[blk * 8 + 4 + k][1];
            const float2 m2 = gm[blk * 8 + 4 + k][2];
            const float2 m3 = gm[blk * 8 + 4 + k][3];
            const int sc = 1 << (3 - k);      // control = wire k
            const int st = 1 << (3 - pt[k]);  // target
#pragma unroll
            for (int i = 0; i < 16; ++i) {
                if ((i & sc) != 0 && (i & st) == 0) {
                    const float2 a0 = amp[i], a1 = amp[i + st];
                    amp[i]      = cadd(cmul(m0, a0), cmul(m1, a1));
                    amp[i + st] = cadd(cmul(m2, a0), cmul(m3, a1));
                }
            }
        }
    }

    // <Z_w> = sum_i |amp_i|^2 * (bit_w(i) ? -1 : +1)
    float ez[4] = {0.f, 0.f, 0.f, 0.f};
#pragma unroll
    for (int i = 0; i < 16; ++i) {
        const float pr = amp[i].x * amp[i].x + amp[i].y * amp[i].y;
#pragma unroll
        for (int w = 0; w < 4; ++w)
            ez[w] += ((i >> (3 - w)) & 1) ? -pr : pr;
    }

    // head: logits[q][k] += ez[q] * W[k][j], j = cb*50 + rb (transposed index)
    const int j = cb * OUTD + rb;
    const float w0 = active ? W[j] : 0.0f;
    const float w1 = active ? W[NPATCH + j] : 0.0f;
    float part[8];
#pragma unroll
    for (int q = 0; q < 4; ++q) {
        part[q * 2 + 0] = ez[q] * w0;
        part[q * 2 + 1] = ez[q] * w1;
    }

    // wave (=block) reduction across 64 lanes
#pragma unroll
    for (int off = 32; off > 0; off >>= 1) {
#pragma unroll
        for (int i = 0; i < 8; ++i)
            part[i] += __shfl_down(part[i], off, 64);
    }

    if (tid == 0) {
#pragma unroll
        for (int i = 0; i < 8; ++i) atomicAdd(&ws_logits[i], part[i]);
        __threadfence();
        const unsigned ticket = atomicAdd(ws_count, 1u);
        if (ticket == (unsigned)(gridDim.x - 1)) {
            __threadfence();
            float l[8];
#pragma unroll
            for (int i = 0; i < 8; ++i) l[i] = atomicAdd(&ws_logits[i], 0.0f);  // coherent read
            const float b0 = bias[0], b1 = bias[1];
#pragma unroll
            for (int q = 0; q < 4; ++q) {
                const float l0 = l[q * 2 + 0] + b0;
                const float l1 = l[q * 2 + 1] + b1;
                const float m = fmaxf(l0, l1);
                const float lse = m + __logf(__expf(l0 - m) + __expf(l1 - m));
                out[q * 2 + 0] = l0 - lse;
                out[q * 2 + 1] = l1 - lse;
            }
        }
    }
}

extern "C" void kernel_launch(void* const* d_in, const int* in_sizes, int n_in,
                              void* d_out, int out_size, void* d_ws, size_t ws_size,
                              hipStream_t stream) {
    const float* img  = (const float*)d_in[0];
    const float* u3p  = (const float*)d_in[1];
    const float* cu3p = (const float*)d_in[2];
    const float* W    = (const float*)d_in[3];
    const float* b    = (const float*)d_in[4];
    float* out = (float*)d_out;

    float* ws_logits = (float*)d_ws;                    // 8 floats
    unsigned* ws_count = (unsigned*)((char*)d_ws + 32); // 1 uint

    hipMemsetAsync(d_ws, 0, 64, stream);  // zero logits + ticket (capturable)
    qconv_fused<<<NBLK, 64, 0, stream>>>(img, u3p, cu3p, W, b,
                                         ws_logits, ws_count, out);
}